// Round 7
// baseline (927.023 us; speedup 1.0000x reference)
//
#include <hip/hip_runtime.h>

// R7 = R6 output kernel (unchanged, 185.7 us) + DIAGNOSTIC fill-mimic probe
// streaming 4.295 GB into d_ws with the IDENTICAL structure (256 blocks x 256
// threads, dense grid-stride marching window). Byte-comparable to rocclr
// fillBufferAligned (6.5 TB/s). Question answered: is the R6 structure at
// fill parity in steady state (then 186 us = 165 floor + fixed overhead), or
// capped at ~5.8 TB/s (then more structural levers needed)?

#define ALIBI_S 4096
#define ALIBI_H 16
#define BLOCK   256
#define GRID    256          // 1 block per CU
#define N_F4    (1u << 26)   // H*S*S/4 float4 elements
#define STRIDE  (GRID * BLOCK)
#define ITERS   (N_F4 / STRIDE)

typedef float f32x4 __attribute__((ext_vector_type(4)));

__global__ __launch_bounds__(BLOCK) void alibi_bias_kernel(
    const float* __restrict__ slopes,
    f32x4* __restrict__ out)
{
    __shared__ float ns_s[ALIBI_H];
    if (threadIdx.x < ALIBI_H) ns_s[threadIdx.x] = -slopes[threadIdx.x];
    __syncthreads();

    unsigned int f = blockIdx.x * BLOCK + threadIdx.x;

#pragma unroll 4
    for (int it = 0; it < ITERS; ++it, f += STRIDE) {
        const unsigned int e = f << 2;
        const int h = (int)(e >> 24);
        const float ns = ns_s[h];
        const int i = (int)((e >> 12) & 4095u);
        const int j = (int)(e & 4095u);

        f32x4 v;
        v.x = (j + 0 > i) ? ns * (float)(j + 0 - i) : 0.0f;
        v.y = (j + 1 > i) ? ns * (float)(j + 1 - i) : 0.0f;
        v.z = (j + 2 > i) ? ns * (float)(j + 2 - i) : 0.0f;
        v.w = (j + 3 > i) ? ns * (float)(j + 3 - i) : 0.0f;

        out[f] = v;
    }
}

// Diagnostic: identical structure, streamed over the full workspace.
__global__ __launch_bounds__(BLOCK) void ws_fillmimic_probe(
    const float* __restrict__ slopes,
    f32x4* __restrict__ ws,
    size_t n4)
{
    __shared__ float ns_s[ALIBI_H];
    if (threadIdx.x < ALIBI_H) ns_s[threadIdx.x] = -slopes[threadIdx.x];
    __syncthreads();

    size_t f = (size_t)blockIdx.x * BLOCK + threadIdx.x;
    const size_t stride = (size_t)GRID * BLOCK;

    for (; f < n4; f += stride) {
        const unsigned int e = (unsigned int)(f << 2);  // pattern wraps mod 2^32: fine
        const int h = (int)((e >> 24) & 15u);
        const float ns = ns_s[h];
        const int i = (int)((e >> 12) & 4095u);
        const int j = (int)(e & 4095u);

        f32x4 v;
        v.x = (j + 0 > i) ? ns * (float)(j + 0 - i) : 0.0f;
        v.y = (j + 1 > i) ? ns * (float)(j + 1 - i) : 0.0f;
        v.z = (j + 2 > i) ? ns * (float)(j + 2 - i) : 0.0f;
        v.w = (j + 3 > i) ? ns * (float)(j + 3 - i) : 0.0f;

        ws[f] = v;
    }
}

extern "C" void kernel_launch(void* const* d_in, const int* in_sizes, int n_in,
                              void* d_out, int out_size, void* d_ws, size_t ws_size,
                              hipStream_t stream) {
    const float* slopes = (const float*)d_in[0];
    f32x4* out = (f32x4*)d_out;

    // The real output kernel (R6 structure, unchanged).
    alibi_bias_kernel<<<GRID, BLOCK, 0, stream>>>(slopes, out);

    // Diagnostic probe over the whole workspace.
    const size_t n4 = ws_size / 16;
    if (n4 > 0) {
        ws_fillmimic_probe<<<GRID, BLOCK, 0, stream>>>(slopes, (f32x4*)d_ws, n4);
    }
}